// Round 8
// baseline (1438.188 us; speedup 1.0000x reference)
//
#include <hip/hip_runtime.h>
#include <stdint.h>

#define EMBED  256
#define HIDDEN 512
#define BATCH  64
#define SEQ    512

typedef _Float16 f16x8 __attribute__((ext_vector_type(8)));
typedef _Float16 f16x4 __attribute__((ext_vector_type(4)));
typedef float    f32x4 __attribute__((ext_vector_type(4)));

// ---------------------------------------------------------------------------
// Fragment packing (A and B share it; permutation-safe):
//   frag[(s*32 + mt)*64 + lane] is an f16x8; element j holds
//     W[k = s*32 + (lane>>4)*8 + j][col = mt*16 + (lane&15)]
// C/D: col = lane&15, row = (lane>>4)*4 + reg.
// ---------------------------------------------------------------------------

#define WIH_FRAGS (8 * 32 * 64 * 8)
#define WHH_FRAGS (16 * 32 * 64 * 8)

__global__ void prep_pack(const float* __restrict__ W_ih,
                          const float* __restrict__ W_hh,
                          unsigned short* __restrict__ wih_p,
                          unsigned short* __restrict__ whh_p) {
    int tid = blockIdx.x * blockDim.x + threadIdx.x;
    if (tid < WIH_FRAGS) {
        int j = tid & 7, l = (tid >> 3) & 63, nt = (tid >> 9) & 31, s = tid >> 14;
        int k   = s * 32 + ((l >> 4) << 3) + j;
        int col = (nt << 4) + (l & 15);
        wih_p[tid] = __builtin_bit_cast(unsigned short, (_Float16)W_ih[k * HIDDEN + col]);
    } else {
        int t2 = tid - WIH_FRAGS;
        if (t2 < WHH_FRAGS) {
            int j = t2 & 7, l = (t2 >> 3) & 63, mt = (t2 >> 9) & 31, s = t2 >> 14;
            int k   = s * 32 + ((l >> 4) << 3) + j;
            int col = (mt << 4) + (l & 15);
            whh_p[t2] = __builtin_bit_cast(unsigned short, (_Float16)W_hh[k * HIDDEN + col]);
        }
    }
}

// ---------------------------------------------------------------------------
// Kernel A: pre = embed @ W_ih + (b_ih + b_hh), f16 in HIGH 1KB of each 2KB
// out row (validated R2/R3/R5/R6).
// ---------------------------------------------------------------------------
__global__ __launch_bounds__(256) void enc_gemm_ih(
    const int* __restrict__ source,
    const float* __restrict__ embedding,
    const unsigned short* __restrict__ wih_p,
    const float* __restrict__ b_ih,
    const float* __restrict__ b_hh,
    float* __restrict__ out)
{
    const int lane = threadIdx.x & 63;
    const int mt   = (blockIdx.x << 2) + (threadIdx.x >> 6);
    const int r0   = mt << 4;
    const int g    = lane >> 4;
    const int c    = lane & 15;

    const int idx = source[r0 + c];
    const float* erow = embedding + (size_t)idx * EMBED;

    f16x8 afrag[8];
#pragma unroll
    for (int s = 0; s < 8; ++s) {
        const float* p = erow + (s << 5) + (g << 3);
        f32x4 f0 = *(const f32x4*)p;
        f32x4 f1 = *(const f32x4*)(p + 4);
        f16x8 a;
        a[0] = (_Float16)f0[0]; a[1] = (_Float16)f0[1];
        a[2] = (_Float16)f0[2]; a[3] = (_Float16)f0[3];
        a[4] = (_Float16)f1[0]; a[5] = (_Float16)f1[1];
        a[6] = (_Float16)f1[2]; a[7] = (_Float16)f1[3];
        afrag[s] = a;
    }

    const f16x8* wp = (const f16x8*)wih_p;
    for (int nt = 0; nt < 32; ++nt) {
        f32x4 acc = {0.f, 0.f, 0.f, 0.f};
#pragma unroll
        for (int s = 0; s < 8; ++s) {
            f16x8 bfr = wp[(((s << 5) + nt) << 6) + lane];
            acc = __builtin_amdgcn_mfma_f32_16x16x32_f16(afrag[s], bfr, acc, 0, 0, 0);
        }
        const int col  = (nt << 4) + c;
        const float bias = b_ih[col] + b_hh[col];
        char* ob = (char*)out + (size_t)(r0 + (g << 2)) * 2048 + 1024 + (col << 1);
#pragma unroll
        for (int r = 0; r < 4; ++r)
            *(_Float16*)(ob + (size_t)r * 2048) = (_Float16)(acc[r] + bias);
    }
}

// --- MEGA asm: 4 MFMAs for one s-group (A=weights, B=h, D=C=acc) ---
#define MM(s) \
  "v_mfma_f32_16x16x32_f16 %[a0], %[w" #s "0], %[h" #s "], %[a0]\n\t" \
  "v_mfma_f32_16x16x32_f16 %[a1], %[w" #s "1], %[h" #s "], %[a1]\n\t" \
  "v_mfma_f32_16x16x32_f16 %[a2], %[w" #s "2], %[h" #s "], %[a2]\n\t" \
  "v_mfma_f32_16x16x32_f16 %[a3], %[w" #s "3], %[h" #s "], %[a3]\n\t"
#define WOPS(s) [w##s##0]"v"(wv[4*s+0]), [w##s##1]"v"(wv[4*s+1]), \
                [w##s##2]"v"(wv[4*s+2]), [w##s##3]"v"(wv[4*s+3])

// ---------------------------------------------------------------------------
// Kernel B: recurrence. 4 blocks x 16 chains, 8 waves; wave w owns m-tiles
// w*4..w*4+3. Weight tiers: s0..10 = 44 frags held in arch VGPRs, residency
// FORCED by one MEGA inline-asm per step that names all 44 frags + 11 h
// frags + 4 accs as simultaneous "v" operands (pressure ~250 -> RA must
// allocate ~256 regs/wave; 8 waves x 256 = full pool, 2 waves/SIMD).
// s11..13 LDS-resident (96 KB); s14..15 streamed from L2 after the asm.
// h double-buffered in LDS [2][16][1024B], XOR-swizzled (validated R2/R5).
// ---------------------------------------------------------------------------
__global__ __launch_bounds__(512) void enc_rnn(
    const unsigned short* __restrict__ whh_p,
    float* __restrict__ out)
{
    extern __shared__ char lds[];
    char* hbase = lds;            // 32 KB: [2][16][1024B], swizzled
    char* wbase = lds + 32768;    // 96 KB: (w*12 + fid)*1024 + lane*16

    const int tid  = threadIdx.x;
    const int lane = tid & 63;
    const int w    = tid >> 6;
    const int g    = lane >> 4;
    const int c    = lane & 15;      // chain
    const int cx   = c & 7;
    const int mt0  = w << 2;

    const f16x8* wp = (const f16x8*)whh_p;

    // LDS tier: s = 11..13
    {
        char* wl0 = wbase + ((w * 12) << 10) + (lane << 4);
#pragma unroll
        for (int fid = 0; fid < 12; ++fid) {
            int s = 11 + (fid >> 2), m = fid & 3;
            *(f16x8*)(wl0 + (fid << 10)) = wp[((s * 32 + mt0 + m) << 6) + lane];
        }
    }
    // zero both h buffers (h_0 = 0)
    for (int i = tid; i < 32768 / 4; i += 512) ((int*)hbase)[i] = 0;

    // VGPR tier: s = 0..10 (44 frags, kept live by the MEGA asm's operands)
    f16x8 wv[44];
#pragma unroll
    for (int f = 0; f < 44; ++f)
        wv[f] = wp[(((f >> 2) * 32 + mt0 + (f & 3)) << 6) + lane];

    __syncthreads();

    // ---- t-invariant addresses (R5-validated) ----
    const int ch = cx >> 2;
    char* hb2 = hbase + (c << 10) + ((g ^ (cx & 3)) << 4);
    char* hev = hb2 + (ch << 6);
    char* hod = hb2 - (ch << 6);
    char* hw[4];
#pragma unroll
    for (int m = 0; m < 4; ++m) {
        int u = (w << 3) | ((m ^ (cx >> 1)) << 1) | ((g >> 1) ^ (cx & 1));
        hw[m] = hbase + (c << 10) + (u << 4) + ((g & 1) << 3);
    }
    char* ga = (char*)out + (size_t)((blockIdx.x << 4) + c) * SEQ * 2048
             + (w << 7) + (g << 3);
    const char* sp14 = (const char*)whh_p + ((14 * 32 + mt0) << 10) + (lane << 4);
    const char* sp15 = (const char*)whh_p + ((15 * 32 + mt0) << 10) + (lane << 4);
    char* wl = wbase + ((w * 12) << 10) + (lane << 4);

    auto STEP = [&](int RB, int RBN, int TB) {
        // h fragments s=0..10 (plain C ds_reads; compiler inserts the waits)
        f16x8 hh[11];
#pragma unroll
        for (int s = 0; s < 11; ++s)
            hh[s] = *(const f16x8*)(((s & 1) ? hod : hev) + (s << 6) + RB);

        f32x4 a0 = {0.f,0.f,0.f,0.f}, a1 = {0.f,0.f,0.f,0.f};
        f32x4 a2 = {0.f,0.f,0.f,0.f}, a3 = {0.f,0.f,0.f,0.f};
        asm volatile(
            MM(0) MM(1) MM(2) MM(3) MM(4) MM(5) MM(6) MM(7) MM(8) MM(9) MM(10)
            : [a0]"+v"(a0), [a1]"+v"(a1), [a2]"+v"(a2), [a3]"+v"(a3)
            : WOPS(0), WOPS(1), WOPS(2), WOPS(3), WOPS(4), WOPS(5), WOPS(6),
              WOPS(7), WOPS(8), WOPS(9), WOPS(10),
              [h0]"v"(hh[0]), [h1]"v"(hh[1]), [h2]"v"(hh[2]), [h3]"v"(hh[3]),
              [h4]"v"(hh[4]), [h5]"v"(hh[5]), [h6]"v"(hh[6]), [h7]"v"(hh[7]),
              [h8]"v"(hh[8]), [h9]"v"(hh[9]), [h10]"v"(hh[10])
            : "memory");

        // stream s14/s15 + pre (issued after the asm so pressure stays <256;
        // consumed ~15 MFMAs later)
        f16x8 sA[4], sB[4];
#pragma unroll
        for (int m = 0; m < 4; ++m) sA[m] = *(const f16x8*)(sp14 + (m << 10));
#pragma unroll
        for (int m = 0; m < 4; ++m) sB[m] = *(const f16x8*)(sp15 + (m << 10));
        f16x4 pre[4];
#pragma unroll
        for (int m = 0; m < 4; ++m)
            pre[m] = *(const f16x4*)(ga + TB + 1024 + (m << 5));

        f32x4 acc[4] = {a0, a1, a2, a3};

        // s = 11..13: LDS tier (intrinsics; compiler-managed waits)
#pragma unroll
        for (int s = 11; s < 14; ++s) {
            f16x8 h = *(const f16x8*)(((s & 1) ? hod : hev) + (s << 6) + RB);
#pragma unroll
            for (int m = 0; m < 4; ++m) {
                f16x8 wvv = *(const f16x8*)(wl + ((((s - 11) << 2) | m) << 10));
                acc[m] = __builtin_amdgcn_mfma_f32_16x16x32_f16(wvv, h, acc[m], 0, 0, 0);
            }
        }
        // s = 14, 15: streamed tier
        {
            f16x8 h = *(const f16x8*)(hev + (14 << 6) + RB);
#pragma unroll
            for (int m = 0; m < 4; ++m)
                acc[m] = __builtin_amdgcn_mfma_f32_16x16x32_f16(sA[m], h, acc[m], 0, 0, 0);
        }
        {
            f16x8 h = *(const f16x8*)(hod + (15 << 6) + RB);
#pragma unroll
            for (int m = 0; m < 4; ++m)
                acc[m] = __builtin_amdgcn_mfma_f32_16x16x32_f16(sB[m], h, acc[m], 0, 0, 0);
        }

        // epilogue: h = tanh(acc + pre); f16 to out low half + LDS next buf
#pragma unroll
        for (int m = 0; m < 4; ++m) {
            f16x4 hv;
#pragma unroll
            for (int r = 0; r < 4; ++r) {
                float x  = acc[m][r] + (float)pre[m][r];
                float e  = __expf(2.0f * x);
                hv[r] = (_Float16)(1.0f - 2.0f * __builtin_amdgcn_rcpf(e + 1.0f));
            }
            *(f16x4*)(ga + TB + (m << 5)) = hv;
            *(f16x4*)(hw[m] + RBN) = hv;
        }
        __syncthreads();
    };

#pragma unroll 1
    for (int tp = 0; tp < SEQ; tp += 2) {
        STEP(0, 16384, 0);
        STEP(16384, 0, 2048);
        ga += 4096;
    }
}

// ---------------------------------------------------------------------------
// Kernel C: in-place expand f16 h (row bytes [0,1024)) -> f32 row.
// ---------------------------------------------------------------------------
__global__ __launch_bounds__(256) void expand_rows(float* __restrict__ out) {
    const int lane = threadIdx.x & 63;
    const int row  = (blockIdx.x << 2) + (threadIdx.x >> 6);
    char* rp = (char*)out + ((size_t)row << 11);
    f16x8 v = *(const f16x8*)(rp + (lane << 4));
    f32x4 lo, hi;
#pragma unroll
    for (int i = 0; i < 4; ++i) { lo[i] = (float)v[i]; hi[i] = (float)v[i + 4]; }
    *(f32x4*)(rp + (lane << 5))      = lo;
    *(f32x4*)(rp + (lane << 5) + 16) = hi;
}

extern "C" void kernel_launch(void* const* d_in, const int* in_sizes, int n_in,
                              void* d_out, int out_size, void* d_ws, size_t ws_size,
                              hipStream_t stream) {
    const int*   source    = (const int*)d_in[0];
    const float* embedding = (const float*)d_in[1];
    const float* W_ih      = (const float*)d_in[2];
    const float* W_hh      = (const float*)d_in[3];
    const float* b_ih      = (const float*)d_in[4];
    const float* b_hh      = (const float*)d_in[5];
    float* out = (float*)d_out;

    unsigned short* wih_p = (unsigned short*)d_ws;          // 256 KB
    unsigned short* whh_p = wih_p + WIH_FRAGS;              // 512 KB

    prep_pack<<<(WIH_FRAGS + WHH_FRAGS) / 256, 256, 0, stream>>>(W_ih, W_hh, wih_p, whh_p);
    enc_gemm_ih<<<512, 256, 0, stream>>>(source, embedding, wih_p, b_ih, b_hh, out);
    enc_rnn<<<4, 512, 131072, stream>>>(whh_p, out);
    expand_rows<<<8192, 256, 0, stream>>>(out);
}